// Round 7
// baseline (1730.318 us; speedup 1.0000x reference)
//
#include <hip/hip_runtime.h>
#include <hip/hip_bf16.h>
#include <stdint.h>

#define ALPHA_F 0.2f
#define K_STEPS 10

typedef __attribute__((ext_vector_type(8))) short short8;
typedef __attribute__((ext_vector_type(4))) float f32x4;
typedef __attribute__((ext_vector_type(4))) unsigned short u16x4;
typedef __attribute__((ext_vector_type(2))) int i32x2;

__device__ __forceinline__ float bf2f(unsigned short u) {
  union { unsigned int i; float f; } v; v.i = ((unsigned int)u) << 16; return v.f;
}
__device__ __forceinline__ unsigned short f2bf(float f) {
  unsigned int x = __float_as_uint(f);
  unsigned int r = (x + 0x7fffu + ((x >> 16) & 1u)) >> 16;
  return (unsigned short)r;
}

__device__ __forceinline__ void glds16(const void* g, void* l) {
  __builtin_amdgcn_global_load_lds(
      (const __attribute__((address_space(1))) void*)g,
      (__attribute__((address_space(3))) void*)l, 16, 0, 0);
}

// ---------------- graph build ----------------

__global__ void k_hist(const int* __restrict__ dst, int* __restrict__ deg, int E) {
  int e = blockIdx.x * blockDim.x + threadIdx.x;
  if (e < E) atomicAdd(&deg[dst[e]], 1);
}

// multi-block exclusive scan of (deg[i]+1): phase A — per-block scan + block sums
__global__ __launch_bounds__(1024)
void k_scanA(const int* __restrict__ deg, int* __restrict__ rowptr,
             int* __restrict__ bsum, int n) {
  __shared__ int buf[2][1024];
  const int tid = threadIdx.x;
  const int gid = blockIdx.x * 1024 + tid;
  int v = (gid < n) ? (deg[gid] + 1) : 0;  // +1 self-loop
  int sel = 0;
  buf[0][tid] = v;
  __syncthreads();
  #pragma unroll
  for (int off = 1; off < 1024; off <<= 1) {
    int t = buf[sel][tid] + ((tid >= off) ? buf[sel][tid - off] : 0);
    buf[sel ^ 1][tid] = t;
    sel ^= 1;
    __syncthreads();
  }
  if (gid < n) rowptr[gid] = buf[sel][tid] - v;  // exclusive within block
  if (tid == 0) bsum[blockIdx.x] = buf[sel][1023];
}

// phase B — serial exclusive scan of block sums (small)
__global__ void k_scanB(int* __restrict__ bsum, int nb) {
  if (threadIdx.x == 0 && blockIdx.x == 0) {
    int acc = 0;
    for (int i = 0; i < nb; ++i) { int t = bsum[i]; bsum[i] = acc; acc += t; }
    bsum[nb] = acc;
  }
}

// phase C — add block offsets; also writes rowptr[n]
__global__ void k_scanC(int* __restrict__ rowptr, const int* __restrict__ bsum,
                        int n, int nb) {
  int gid = blockIdx.x * blockDim.x + threadIdx.x;
  if (gid < n) rowptr[gid] += bsum[gid >> 10];
  else if (gid == n) rowptr[n] = bsum[nb];
}

__global__ void k_dinv_cursor(const int* __restrict__ deg, const int* __restrict__ rowptr,
                              float* __restrict__ dinv, int* __restrict__ cursor, int n) {
  int i = blockIdx.x * blockDim.x + threadIdx.x;
  if (i < n) {
    dinv[i] = 1.0f / sqrtf((float)(deg[i] + 1));
    cursor[i] = rowptr[i];
  }
}

// edge[pos] = {src, bits(dinv[src])}
__global__ void k_scatter(const int* __restrict__ src, const int* __restrict__ dst,
                          int* __restrict__ cursor, i32x2* __restrict__ edge,
                          const float* __restrict__ dinv, int E, int n) {
  int idx = blockIdx.x * blockDim.x + threadIdx.x;
  if (idx >= E + n) return;
  int s, d;
  if (idx < E) { s = src[idx]; d = dst[idx]; }
  else         { s = d = idx - E; }
  int pos = atomicAdd(&cursor[d], 1);
  i32x2 e;
  e.x = s;
  e.y = __float_as_int(dinv[s]);
  edge[pos] = e;
}

// ---------------- degree-balanced node ordering (counting sort by deg) ----------------

__global__ void k_dhist(const int* __restrict__ deg, int* __restrict__ bins, int n) {
  int i = blockIdx.x * blockDim.x + threadIdx.x;
  if (i < n) atomicAdd(&bins[min(deg[i], 1023)], 1);
}

// single-block 1024-wide exclusive scan of bins (in place)
__global__ __launch_bounds__(1024)
void k_dscan(int* __restrict__ bins) {
  __shared__ int buf[2][1024];
  const int tid = threadIdx.x;
  int v = bins[tid];
  int sel = 0;
  buf[0][tid] = v;
  __syncthreads();
  #pragma unroll
  for (int off = 1; off < 1024; off <<= 1) {
    int t = buf[sel][tid] + ((tid >= off) ? buf[sel][tid - off] : 0);
    buf[sel ^ 1][tid] = t;
    sel ^= 1;
    __syncthreads();
  }
  bins[tid] = buf[sel][tid] - v;  // exclusive
}

__global__ void k_dorder(const int* __restrict__ deg, int* __restrict__ bins,
                         int* __restrict__ order, int n) {
  int i = blockIdx.x * blockDim.x + threadIdx.x;
  if (i < n) {
    int pos = atomicAdd(&bins[min(deg[i], 1023)], 1);
    order[pos] = i;
  }
}

// ---------------- converts ----------------

// fp32 -> bf16, 8 elems/thread, zero-fill pad rows
__global__ void k_f2b8(const float* __restrict__ src, unsigned short* __restrict__ dst,
                       int validRows, int cols, long total8) {
  long idx = (long)blockIdx.x * blockDim.x + threadIdx.x;
  if (idx >= total8) return;
  size_t base = (size_t)idx * 8;
  int row = (int)(base / (size_t)cols);
  uint4 o;
  if (row < validRows) {
    const float4 f0 = *reinterpret_cast<const float4*>(src + base);
    const float4 f1 = *reinterpret_cast<const float4*>(src + base + 4);
    o.x = f2bf(f0.x) | ((unsigned)f2bf(f0.y) << 16);
    o.y = f2bf(f0.z) | ((unsigned)f2bf(f0.w) << 16);
    o.z = f2bf(f1.x) | ((unsigned)f2bf(f1.y) << 16);
    o.w = f2bf(f1.z) | ((unsigned)f2bf(f1.w) << 16);
  } else {
    o = make_uint4(0, 0, 0, 0);
  }
  *reinterpret_cast<uint4*>(dst + base) = o;
}

// W [K][Nw] fp32 -> Wt [Nw][K] bf16, LDS-tiled 32x32 (coalesced both sides)
__global__ __launch_bounds__(256)
void k_wtrans(const float* __restrict__ W, unsigned short* __restrict__ Wt,
              int K, int Nw) {
  __shared__ float tile[32][33];
  const int bn = blockIdx.x * 32;  // Nw dir
  const int bk = blockIdx.y * 32;  // K dir
  const int tx = threadIdx.x & 31;
  const int ty = threadIdx.x >> 5;  // 0..7
  #pragma unroll
  for (int r = 0; r < 32; r += 8)
    tile[r + ty][tx] = W[(size_t)(bk + r + ty) * Nw + bn + tx];
  __syncthreads();
  #pragma unroll
  for (int r = 0; r < 32; r += 8)
    Wt[(size_t)(bn + r + ty) * K + bk + tx] = f2bf(tile[tx][r + ty]);
}

// ---------------- MFMA GEMM ----------------
// C[M][Nn] = A[M][K]_bf16 @ Bt[Nn][K]_bf16^T + bias, 128x128 tile, BK=32,
// 256 threads = 4 waves (2x2), each wave 64x64 = 4x4 fragments of 16x16x32.

template<bool OUT_BF16, bool RELU>
__global__ __launch_bounds__(256)
void k_gemm_mfma(const unsigned short* __restrict__ A,
                 const unsigned short* __restrict__ Bt,
                 const float* __restrict__ bias,
                 void* __restrict__ C, int Nn, int K) {
  __shared__ unsigned short As[128 * 32];
  __shared__ unsigned short Bs[128 * 32];
  const int tid = threadIdx.x;
  const int lane = tid & 63;
  const int wid = tid >> 6;
  const int wr = wid >> 1, wc = wid & 1;
  const int bm = blockIdx.y * 128;
  const int bn = blockIdx.x * 128;

  f32x4 acc[4][4];
  #pragma unroll
  for (int i = 0; i < 4; ++i)
    #pragma unroll
    for (int j = 0; j < 4; ++j) acc[i][j] = (f32x4)0.f;

  const int srow = tid >> 2;
  const int skg = (tid & 3) << 3;
  const unsigned short* Ag = A + (size_t)(bm + srow) * K + skg;
  const unsigned short* Bg = Bt + (size_t)(bn + srow) * K + skg;
  unsigned short* lA = As + (wid << 9);
  unsigned short* lB = Bs + (wid << 9);

  const int frow = lane & 15;
  const int fk = (lane >> 4) << 3;

  for (int k0 = 0; k0 < K; k0 += 32) {
    __syncthreads();
    glds16(Ag + k0, lA);
    glds16(Ag + (size_t)64 * K + k0, lA + 2048);
    glds16(Bg + k0, lB);
    glds16(Bg + (size_t)64 * K + k0, lB + 2048);
    __syncthreads();

    short8 af[4], bq[4];
    #pragma unroll
    for (int mi = 0; mi < 4; ++mi)
      af[mi] = *reinterpret_cast<const short8*>(&As[(wr * 64 + mi * 16 + frow) * 32 + fk]);
    #pragma unroll
    for (int ni = 0; ni < 4; ++ni)
      bq[ni] = *reinterpret_cast<const short8*>(&Bs[(wc * 64 + ni * 16 + frow) * 32 + fk]);
    #pragma unroll
    for (int mi = 0; mi < 4; ++mi)
      #pragma unroll
      for (int ni = 0; ni < 4; ++ni)
        acc[mi][ni] = __builtin_amdgcn_mfma_f32_16x16x32_bf16(af[mi], bq[ni], acc[mi][ni], 0, 0, 0);
  }

  const int r0 = bm + wr * 64;
  const int c0 = bn + wc * 64;
  #pragma unroll
  for (int ni = 0; ni < 4; ++ni) {
    const int c = c0 + ni * 16 + (lane & 15);
    const float bv = bias[c];
    #pragma unroll
    for (int mi = 0; mi < 4; ++mi) {
      #pragma unroll
      for (int r = 0; r < 4; ++r) {
        const int row = r0 + mi * 16 + ((lane >> 4) << 2) + r;
        float v = acc[mi][ni][r] + bv;
        if constexpr (RELU) v = fmaxf(v, 0.f);
        if constexpr (OUT_BF16)
          ((unsigned short*)C)[(size_t)row * Nn + c] = f2bf(v);
        else
          ((float*)C)[(size_t)row * Nn + c] = v;
      }
    }
  }
}

// ---------------- APPNP propagation step ----------------
// bf16 state [N][256], 1 wave per node (via degree-sorted order[]), lane = 4 dims.
// 2-stage software-pipelined edge loop.

#define NTLD(p) __builtin_nontemporal_load(p)

template<bool FINAL>
__global__ __launch_bounds__(256)
void k_appnp_b16(const unsigned short* __restrict__ hprev,
                 const unsigned short* __restrict__ h0b,
                 void* __restrict__ outp,
                 const int* __restrict__ rowptr,
                 const i32x2* __restrict__ edge,
                 const float* __restrict__ dinv,
                 const int* __restrict__ order, int n) {
  const int lane = threadIdx.x & 63;
  const int slot = blockIdx.x * 4 + (threadIdx.x >> 6);
  if (slot >= n) return;
  const int i = order[slot];
  const int beg = rowptr[i];
  const int end = rowptr[i + 1];
  const int d = lane << 2;
  float a0 = 0.f, a1 = 0.f, a2 = 0.f, a3 = 0.f;

  auto gat = [&](int j) -> u16x4 {
    return *reinterpret_cast<const u16x4*>(hprev + (size_t)j * 256 + d);
  };
  auto accq = [&](float w, u16x4 v) {
    a0 += w * bf2f(v.x); a1 += w * bf2f(v.y);
    a2 += w * bf2f(v.z); a3 += w * bf2f(v.w);
  };

  const int quads = (end - beg) >> 2;
  int e = beg;
  if (quads >= 2) {
    i32x2 t0 = NTLD(edge + e),     t1 = NTLD(edge + e + 1);
    i32x2 t2 = NTLD(edge + e + 2), t3 = NTLD(edge + e + 3);
    i32x2 B0 = NTLD(edge + e + 4), B1 = NTLD(edge + e + 5);
    i32x2 B2 = NTLD(edge + e + 6), B3 = NTLD(edge + e + 7);
    u16x4 V0 = gat(t0.x), V1 = gat(t1.x), V2 = gat(t2.x), V3 = gat(t3.x);
    float w0 = __int_as_float(t0.y), w1 = __int_as_float(t1.y);
    float w2 = __int_as_float(t2.y), w3 = __int_as_float(t3.y);
    for (int q = 2; q < quads; ++q) {
      const i32x2* ep = edge + e + (q << 2);
      const i32x2 C0 = NTLD(ep),     C1 = NTLD(ep + 1);
      const i32x2 C2 = NTLD(ep + 2), C3 = NTLD(ep + 3);
      const u16x4 U0 = gat(B0.x), U1 = gat(B1.x), U2 = gat(B2.x), U3 = gat(B3.x);
      const float x0 = __int_as_float(B0.y), x1 = __int_as_float(B1.y);
      const float x2 = __int_as_float(B2.y), x3 = __int_as_float(B3.y);
      accq(w0, V0); accq(w1, V1); accq(w2, V2); accq(w3, V3);
      V0 = U0; V1 = U1; V2 = U2; V3 = U3;
      w0 = x0; w1 = x1; w2 = x2; w3 = x3;
      B0 = C0; B1 = C1; B2 = C2; B3 = C3;
    }
    const u16x4 U0 = gat(B0.x), U1 = gat(B1.x), U2 = gat(B2.x), U3 = gat(B3.x);
    accq(w0, V0); accq(w1, V1); accq(w2, V2); accq(w3, V3);
    accq(__int_as_float(B0.y), U0); accq(__int_as_float(B1.y), U1);
    accq(__int_as_float(B2.y), U2); accq(__int_as_float(B3.y), U3);
    e += quads << 2;
  } else if (quads == 1) {
    const i32x2 t0 = NTLD(edge + e),     t1 = NTLD(edge + e + 1);
    const i32x2 t2 = NTLD(edge + e + 2), t3 = NTLD(edge + e + 3);
    const u16x4 V0 = gat(t0.x), V1 = gat(t1.x), V2 = gat(t2.x), V3 = gat(t3.x);
    accq(__int_as_float(t0.y), V0); accq(__int_as_float(t1.y), V1);
    accq(__int_as_float(t2.y), V2); accq(__int_as_float(t3.y), V3);
    e += 4;
  }
  for (; e < end; ++e) {
    const i32x2 ee = NTLD(edge + e);
    accq(__int_as_float(ee.y), gat(ee.x));
  }

  const float s = (1.0f - ALPHA_F) * dinv[i];
  const u16x4 hv = NTLD(reinterpret_cast<const u16x4*>(h0b + (size_t)i * 256 + d));
  const float o0 = s * a0 + ALPHA_F * bf2f(hv.x);
  const float o1 = s * a1 + ALPHA_F * bf2f(hv.y);
  const float o2 = s * a2 + ALPHA_F * bf2f(hv.z);
  const float o3 = s * a3 + ALPHA_F * bf2f(hv.w);
  if constexpr (FINAL) {
    f32x4 o; o.x = o0; o.y = o1; o.z = o2; o.w = o3;
    __builtin_nontemporal_store(o, reinterpret_cast<f32x4*>((float*)outp + (size_t)i * 256 + d));
  } else {
    u16x4 o;
    o.x = f2bf(o0); o.y = f2bf(o1); o.z = f2bf(o2); o.w = f2bf(o3);
    *reinterpret_cast<u16x4*>((unsigned short*)outp + (size_t)i * 256 + d) = o;
  }
}

// ---------------- launch ----------------

extern "C" void kernel_launch(void* const* d_in, const int* in_sizes, int n_in,
                              void* d_out, int out_size, void* d_ws, size_t ws_size,
                              hipStream_t stream) {
  const float* x  = (const float*)d_in[0];
  const int*   ei = (const int*)d_in[1];
  const float* W1 = (const float*)d_in[2];
  const float* b1 = (const float*)d_in[3];
  const float* W2 = (const float*)d_in[4];
  const float* b2 = (const float*)d_in[5];
  const float* W3 = (const float*)d_in[6];
  const float* b3 = (const float*)d_in[7];

  const int HID  = in_sizes[3];            // 512
  const int IN   = in_sizes[2] / HID;      // 512
  const int OUTD = in_sizes[7];            // 256
  const int E    = in_sizes[1] / 2;        // 1,600,000
  const int N    = in_sizes[0] / IN;       // 50,000
  const int Mpad = (N + 127) & ~127;       // 50,048
  const int* src = ei;
  const int* dst = ei + E;

  char* ws = (char*)d_ws;
  size_t off = 0;
  auto alloc = [&](size_t bytes) {
    char* p = ws + off;
    off += (bytes + 255) & ~(size_t)255;
    return p;
  };
  // R1: xb [Mpad][IN] bf16 -> h2 [Mpad][HID] bf16 -> stateB bf16 [N][256]
  char* R1 = alloc((size_t)Mpad * ((IN > HID) ? IN : HID) * 2);
  // R2: h1 [Mpad][HID] bf16 -> stateA bf16 [N][256]
  char* R2 = alloc((size_t)Mpad * HID * 2);
  // R4: h0b bf16 [Mpad][OUTD] (persistent teleport term)
  char* R4 = alloc((size_t)Mpad * OUTD * 2);
  int*   deg    = (int*)alloc((size_t)N * 4);
  int*   rowptr = (int*)alloc((size_t)(N + 1) * 4);
  int*   cursor = (int*)alloc((size_t)N * 4);
  float* dinv   = (float*)alloc((size_t)N * 4);
  int*   bsum   = (int*)alloc((size_t)256 * 4);
  int*   bins   = (int*)alloc((size_t)1024 * 4);
  int*   order  = (int*)alloc((size_t)N * 4);
  i32x2* edge   = (i32x2*)alloc((size_t)(E + N + 8) * 8);  // +8: prefetch pad
  unsigned short* W1t = (unsigned short*)alloc((size_t)IN * HID * 2);
  unsigned short* W2t = (unsigned short*)alloc((size_t)HID * HID * 2);
  unsigned short* W3t = (unsigned short*)alloc((size_t)HID * OUTD * 2);
  (void)ws_size; (void)n_in; (void)out_size;

  unsigned short* xb = (unsigned short*)R1;
  unsigned short* h1 = (unsigned short*)R2;
  unsigned short* h2 = (unsigned short*)R1;
  unsigned short* h0b = (unsigned short*)R4;
  unsigned short* stateA = (unsigned short*)R2;
  unsigned short* stateB = (unsigned short*)R1;

  // graph build
  hipMemsetAsync(deg, 0, (size_t)N * 4, stream);
  hipMemsetAsync(bins, 0, (size_t)1024 * 4, stream);
  k_hist<<<(E + 255) / 256, 256, 0, stream>>>(dst, deg, E);
  const int nb = (N + 1023) / 1024;
  k_scanA<<<nb, 1024, 0, stream>>>(deg, rowptr, bsum, N);
  k_scanB<<<1, 64, 0, stream>>>(bsum, nb);
  k_scanC<<<(N + 256) / 256, 256, 0, stream>>>(rowptr, bsum, N, nb);
  k_dinv_cursor<<<(N + 255) / 256, 256, 0, stream>>>(deg, rowptr, dinv, cursor, N);
  k_scatter<<<(E + N + 255) / 256, 256, 0, stream>>>(src, dst, cursor, edge, dinv, E, N);
  // degree-balanced order
  k_dhist<<<(N + 255) / 256, 256, 0, stream>>>(deg, bins, N);
  k_dscan<<<1, 1024, 0, stream>>>(bins);
  k_dorder<<<(N + 255) / 256, 256, 0, stream>>>(deg, bins, order, N);

  // converts
  {
    long total8 = (long)Mpad * IN / 8;
    k_f2b8<<<(int)((total8 + 255) / 256), 256, 0, stream>>>(x, xb, N, IN, total8);
    dim3 tb(256);
    k_wtrans<<<dim3(HID / 32, IN / 32), tb, 0, stream>>>(W1, W1t, IN, HID);
    k_wtrans<<<dim3(HID / 32, HID / 32), tb, 0, stream>>>(W2, W2t, HID, HID);
    k_wtrans<<<dim3(OUTD / 32, HID / 32), tb, 0, stream>>>(W3, W3t, HID, OUTD);
  }

  // MLP encoder (MFMA); GEMM3 emits bf16 h0b directly
  {
    dim3 blk(256);
    dim3 g1(HID / 128, Mpad / 128);
    k_gemm_mfma<true, true><<<g1, blk, 0, stream>>>(xb, W1t, b1, h1, HID, IN);
    k_gemm_mfma<true, true><<<g1, blk, 0, stream>>>(h1, W2t, b2, h2, HID, HID);
    dim3 g3(OUTD / 128, Mpad / 128);
    k_gemm_mfma<true, false><<<g3, blk, 0, stream>>>(h2, W3t, b3, h0b, OUTD, HID);
  }

  // APPNP propagation: step0 reads h0b; steps ping-pong stateA/B; final -> d_out
  {
    const int nblk = (N + 3) / 4;
    const unsigned short* cur = h0b;
    for (int step = 0; step < K_STEPS - 1; ++step) {
      unsigned short* dbuf = (step % 2 == 0) ? stateA : stateB;
      k_appnp_b16<false><<<nblk, 256, 0, stream>>>(cur, h0b, dbuf, rowptr, edge, dinv, order, N);
      cur = dbuf;
    }
    k_appnp_b16<true><<<nblk, 256, 0, stream>>>(cur, h0b, d_out, rowptr, edge, dinv, order, N);
  }
}

// Round 8
// 1510.660 us; speedup vs baseline: 1.1454x; 1.1454x over previous
//
#include <hip/hip_runtime.h>
#include <hip/hip_bf16.h>
#include <stdint.h>

#define ALPHA_F 0.2f
#define K_STEPS 10

typedef __attribute__((ext_vector_type(8))) short short8;
typedef __attribute__((ext_vector_type(4))) float f32x4;
typedef __attribute__((ext_vector_type(4))) unsigned short u16x4;
typedef __attribute__((ext_vector_type(2))) int i32x2;

__device__ __forceinline__ float bf2f(unsigned short u) {
  union { unsigned int i; float f; } v; v.i = ((unsigned int)u) << 16; return v.f;
}
__device__ __forceinline__ unsigned short f2bf(float f) {
  unsigned int x = __float_as_uint(f);
  unsigned int r = (x + 0x7fffu + ((x >> 16) & 1u)) >> 16;
  return (unsigned short)r;
}

__device__ __forceinline__ void glds16(const void* g, void* l) {
  __builtin_amdgcn_global_load_lds(
      (const __attribute__((address_space(1))) void*)g,
      (__attribute__((address_space(3))) void*)l, 16, 0, 0);
}

// ---------------- graph build ----------------

__global__ void k_hist(const int* __restrict__ dst, int* __restrict__ deg, int E) {
  int e = blockIdx.x * blockDim.x + threadIdx.x;
  if (e < E) atomicAdd(&deg[dst[e]], 1);
}

// multi-block exclusive scan of (deg[i]+1): phase A — per-block scan + block sums
__global__ __launch_bounds__(1024)
void k_scanA(const int* __restrict__ deg, int* __restrict__ rowptr,
             int* __restrict__ bsum, int n) {
  __shared__ int buf[2][1024];
  const int tid = threadIdx.x;
  const int gid = blockIdx.x * 1024 + tid;
  int v = (gid < n) ? (deg[gid] + 1) : 0;  // +1 self-loop
  int sel = 0;
  buf[0][tid] = v;
  __syncthreads();
  #pragma unroll
  for (int off = 1; off < 1024; off <<= 1) {
    int t = buf[sel][tid] + ((tid >= off) ? buf[sel][tid - off] : 0);
    buf[sel ^ 1][tid] = t;
    sel ^= 1;
    __syncthreads();
  }
  if (gid < n) rowptr[gid] = buf[sel][tid] - v;  // exclusive within block
  if (tid == 0) bsum[blockIdx.x] = buf[sel][1023];
}

// phase B — serial exclusive scan of block sums (small)
__global__ void k_scanB(int* __restrict__ bsum, int nb) {
  if (threadIdx.x == 0 && blockIdx.x == 0) {
    int acc = 0;
    for (int i = 0; i < nb; ++i) { int t = bsum[i]; bsum[i] = acc; acc += t; }
    bsum[nb] = acc;
  }
}

// phase C — add block offsets, write rowptr[n], and produce dinv/cursor (fused)
__global__ void k_scanC(int* __restrict__ rowptr, const int* __restrict__ bsum,
                        const int* __restrict__ deg, float* __restrict__ dinv,
                        int* __restrict__ cursor, int n, int nb) {
  int gid = blockIdx.x * blockDim.x + threadIdx.x;
  if (gid < n) {
    int r = rowptr[gid] + bsum[gid >> 10];
    rowptr[gid] = r;
    cursor[gid] = r;
    dinv[gid] = 1.0f / sqrtf((float)(deg[gid] + 1));
  } else if (gid == n) {
    rowptr[n] = bsum[nb];
  }
}

// edge[pos] = {src, bits(dinv[src])}
__global__ void k_scatter(const int* __restrict__ src, const int* __restrict__ dst,
                          int* __restrict__ cursor, i32x2* __restrict__ edge,
                          const float* __restrict__ dinv, int E, int n) {
  int idx = blockIdx.x * blockDim.x + threadIdx.x;
  if (idx >= E + n) return;
  int s, d;
  if (idx < E) { s = src[idx]; d = dst[idx]; }
  else         { s = d = idx - E; }
  int pos = atomicAdd(&cursor[d], 1);
  i32x2 e;
  e.x = s;
  e.y = __float_as_int(dinv[s]);
  edge[pos] = e;
}

// ---------------- converts ----------------

// fp32 -> bf16, 8 elems/thread, zero-fill pad rows
__global__ void k_f2b8(const float* __restrict__ src, unsigned short* __restrict__ dst,
                       int validRows, int cols, long total8) {
  long idx = (long)blockIdx.x * blockDim.x + threadIdx.x;
  if (idx >= total8) return;
  size_t base = (size_t)idx * 8;
  int row = (int)(base / (size_t)cols);
  uint4 o;
  if (row < validRows) {
    const float4 f0 = *reinterpret_cast<const float4*>(src + base);
    const float4 f1 = *reinterpret_cast<const float4*>(src + base + 4);
    o.x = f2bf(f0.x) | ((unsigned)f2bf(f0.y) << 16);
    o.y = f2bf(f0.z) | ((unsigned)f2bf(f0.w) << 16);
    o.z = f2bf(f1.x) | ((unsigned)f2bf(f1.y) << 16);
    o.w = f2bf(f1.z) | ((unsigned)f2bf(f1.w) << 16);
  } else {
    o = make_uint4(0, 0, 0, 0);
  }
  *reinterpret_cast<uint4*>(dst + base) = o;
}

// W [K][Nw] fp32 -> Wt [Nw][K] bf16, LDS-tiled 32x32 (coalesced both sides)
__global__ __launch_bounds__(256)
void k_wtrans(const float* __restrict__ W, unsigned short* __restrict__ Wt,
              int K, int Nw) {
  __shared__ float tile[32][33];
  const int bn = blockIdx.x * 32;  // Nw dir
  const int bk = blockIdx.y * 32;  // K dir
  const int tx = threadIdx.x & 31;
  const int ty = threadIdx.x >> 5;  // 0..7
  #pragma unroll
  for (int r = 0; r < 32; r += 8)
    tile[r + ty][tx] = W[(size_t)(bk + r + ty) * Nw + bn + tx];
  __syncthreads();
  #pragma unroll
  for (int r = 0; r < 32; r += 8)
    Wt[(size_t)(bn + r + ty) * K + bk + tx] = f2bf(tile[tx][r + ty]);
}

// ---------------- MFMA GEMM ----------------
// C[M][Nn] = A[M][K]_bf16 @ Bt[Nn][K]_bf16^T + bias, 128x128 tile, BK=32,
// 256 threads = 4 waves (2x2), each wave 64x64 = 4x4 fragments of 16x16x32.

template<bool OUT_BF16, bool RELU>
__global__ __launch_bounds__(256)
void k_gemm_mfma(const unsigned short* __restrict__ A,
                 const unsigned short* __restrict__ Bt,
                 const float* __restrict__ bias,
                 void* __restrict__ C, int Nn, int K) {
  __shared__ unsigned short As[128 * 32];
  __shared__ unsigned short Bs[128 * 32];
  const int tid = threadIdx.x;
  const int lane = tid & 63;
  const int wid = tid >> 6;
  const int wr = wid >> 1, wc = wid & 1;
  const int bm = blockIdx.y * 128;
  const int bn = blockIdx.x * 128;

  f32x4 acc[4][4];
  #pragma unroll
  for (int i = 0; i < 4; ++i)
    #pragma unroll
    for (int j = 0; j < 4; ++j) acc[i][j] = (f32x4)0.f;

  const int srow = tid >> 2;
  const int skg = (tid & 3) << 3;
  const unsigned short* Ag = A + (size_t)(bm + srow) * K + skg;
  const unsigned short* Bg = Bt + (size_t)(bn + srow) * K + skg;
  unsigned short* lA = As + (wid << 9);
  unsigned short* lB = Bs + (wid << 9);

  const int frow = lane & 15;
  const int fk = (lane >> 4) << 3;

  for (int k0 = 0; k0 < K; k0 += 32) {
    __syncthreads();
    glds16(Ag + k0, lA);
    glds16(Ag + (size_t)64 * K + k0, lA + 2048);
    glds16(Bg + k0, lB);
    glds16(Bg + (size_t)64 * K + k0, lB + 2048);
    __syncthreads();

    short8 af[4], bq[4];
    #pragma unroll
    for (int mi = 0; mi < 4; ++mi)
      af[mi] = *reinterpret_cast<const short8*>(&As[(wr * 64 + mi * 16 + frow) * 32 + fk]);
    #pragma unroll
    for (int ni = 0; ni < 4; ++ni)
      bq[ni] = *reinterpret_cast<const short8*>(&Bs[(wc * 64 + ni * 16 + frow) * 32 + fk]);
    #pragma unroll
    for (int mi = 0; mi < 4; ++mi)
      #pragma unroll
      for (int ni = 0; ni < 4; ++ni)
        acc[mi][ni] = __builtin_amdgcn_mfma_f32_16x16x32_bf16(af[mi], bq[ni], acc[mi][ni], 0, 0, 0);
  }

  const int r0 = bm + wr * 64;
  const int c0 = bn + wc * 64;
  #pragma unroll
  for (int ni = 0; ni < 4; ++ni) {
    const int c = c0 + ni * 16 + (lane & 15);
    const float bv = bias[c];
    #pragma unroll
    for (int mi = 0; mi < 4; ++mi) {
      #pragma unroll
      for (int r = 0; r < 4; ++r) {
        const int row = r0 + mi * 16 + ((lane >> 4) << 2) + r;
        float v = acc[mi][ni][r] + bv;
        if constexpr (RELU) v = fmaxf(v, 0.f);
        if constexpr (OUT_BF16)
          ((unsigned short*)C)[(size_t)row * Nn + c] = f2bf(v);
        else
          ((float*)C)[(size_t)row * Nn + c] = v;
      }
    }
  }
}

// ---------------- APPNP propagation step ----------------
// bf16 state [N][256], 1 wave per node, lane = 4 dims (u16x4). 2-stage
// software-pipelined edge loop (edges 2 quads ahead, gathers 1 quad ahead).

#define NTLD(p) __builtin_nontemporal_load(p)

template<bool FINAL>
__global__ __launch_bounds__(256)
void k_appnp_b16(const unsigned short* __restrict__ hprev,
                 const unsigned short* __restrict__ h0b,
                 void* __restrict__ outp,
                 const int* __restrict__ rowptr,
                 const i32x2* __restrict__ edge,
                 const float* __restrict__ dinv, int n) {
  const int lane = threadIdx.x & 63;
  const int i = blockIdx.x * 4 + (threadIdx.x >> 6);
  if (i >= n) return;
  const int beg = rowptr[i];
  const int end = rowptr[i + 1];
  const int d = lane << 2;
  float a0 = 0.f, a1 = 0.f, a2 = 0.f, a3 = 0.f;

  auto gat = [&](int j) -> u16x4 {
    return *reinterpret_cast<const u16x4*>(hprev + (size_t)j * 256 + d);
  };
  auto accq = [&](float w, u16x4 v) {
    a0 += w * bf2f(v.x); a1 += w * bf2f(v.y);
    a2 += w * bf2f(v.z); a3 += w * bf2f(v.w);
  };

  const int quads = (end - beg) >> 2;
  int e = beg;
  if (quads >= 2) {
    i32x2 t0 = NTLD(edge + e),     t1 = NTLD(edge + e + 1);
    i32x2 t2 = NTLD(edge + e + 2), t3 = NTLD(edge + e + 3);
    i32x2 B0 = NTLD(edge + e + 4), B1 = NTLD(edge + e + 5);
    i32x2 B2 = NTLD(edge + e + 6), B3 = NTLD(edge + e + 7);
    u16x4 V0 = gat(t0.x), V1 = gat(t1.x), V2 = gat(t2.x), V3 = gat(t3.x);
    float w0 = __int_as_float(t0.y), w1 = __int_as_float(t1.y);
    float w2 = __int_as_float(t2.y), w3 = __int_as_float(t3.y);
    for (int q = 2; q < quads; ++q) {
      const i32x2* ep = edge + e + (q << 2);
      const i32x2 C0 = NTLD(ep),     C1 = NTLD(ep + 1);
      const i32x2 C2 = NTLD(ep + 2), C3 = NTLD(ep + 3);
      const u16x4 U0 = gat(B0.x), U1 = gat(B1.x), U2 = gat(B2.x), U3 = gat(B3.x);
      const float x0 = __int_as_float(B0.y), x1 = __int_as_float(B1.y);
      const float x2 = __int_as_float(B2.y), x3 = __int_as_float(B3.y);
      accq(w0, V0); accq(w1, V1); accq(w2, V2); accq(w3, V3);
      V0 = U0; V1 = U1; V2 = U2; V3 = U3;
      w0 = x0; w1 = x1; w2 = x2; w3 = x3;
      B0 = C0; B1 = C1; B2 = C2; B3 = C3;
    }
    const u16x4 U0 = gat(B0.x), U1 = gat(B1.x), U2 = gat(B2.x), U3 = gat(B3.x);
    accq(w0, V0); accq(w1, V1); accq(w2, V2); accq(w3, V3);
    accq(__int_as_float(B0.y), U0); accq(__int_as_float(B1.y), U1);
    accq(__int_as_float(B2.y), U2); accq(__int_as_float(B3.y), U3);
    e += quads << 2;
  } else if (quads == 1) {
    const i32x2 t0 = NTLD(edge + e),     t1 = NTLD(edge + e + 1);
    const i32x2 t2 = NTLD(edge + e + 2), t3 = NTLD(edge + e + 3);
    const u16x4 V0 = gat(t0.x), V1 = gat(t1.x), V2 = gat(t2.x), V3 = gat(t3.x);
    accq(__int_as_float(t0.y), V0); accq(__int_as_float(t1.y), V1);
    accq(__int_as_float(t2.y), V2); accq(__int_as_float(t3.y), V3);
    e += 4;
  }
  for (; e < end; ++e) {
    const i32x2 ee = NTLD(edge + e);
    accq(__int_as_float(ee.y), gat(ee.x));
  }

  const float s = (1.0f - ALPHA_F) * dinv[i];
  const u16x4 hv = NTLD(reinterpret_cast<const u16x4*>(h0b + (size_t)i * 256 + d));
  const float o0 = s * a0 + ALPHA_F * bf2f(hv.x);
  const float o1 = s * a1 + ALPHA_F * bf2f(hv.y);
  const float o2 = s * a2 + ALPHA_F * bf2f(hv.z);
  const float o3 = s * a3 + ALPHA_F * bf2f(hv.w);
  if constexpr (FINAL) {
    f32x4 o; o.x = o0; o.y = o1; o.z = o2; o.w = o3;
    __builtin_nontemporal_store(o, reinterpret_cast<f32x4*>((float*)outp + (size_t)i * 256 + d));
  } else {
    u16x4 o;
    o.x = f2bf(o0); o.y = f2bf(o1); o.z = f2bf(o2); o.w = f2bf(o3);
    *reinterpret_cast<u16x4*>((unsigned short*)outp + (size_t)i * 256 + d) = o;
  }
}

// ---------------- launch ----------------

extern "C" void kernel_launch(void* const* d_in, const int* in_sizes, int n_in,
                              void* d_out, int out_size, void* d_ws, size_t ws_size,
                              hipStream_t stream) {
  const float* x  = (const float*)d_in[0];
  const int*   ei = (const int*)d_in[1];
  const float* W1 = (const float*)d_in[2];
  const float* b1 = (const float*)d_in[3];
  const float* W2 = (const float*)d_in[4];
  const float* b2 = (const float*)d_in[5];
  const float* W3 = (const float*)d_in[6];
  const float* b3 = (const float*)d_in[7];

  const int HID  = in_sizes[3];            // 512
  const int IN   = in_sizes[2] / HID;      // 512
  const int OUTD = in_sizes[7];            // 256
  const int E    = in_sizes[1] / 2;        // 1,600,000
  const int N    = in_sizes[0] / IN;       // 50,000
  const int Mpad = (N + 127) & ~127;       // 50,048
  const int* src = ei;
  const int* dst = ei + E;

  char* ws = (char*)d_ws;
  size_t off = 0;
  auto alloc = [&](size_t bytes) {
    char* p = ws + off;
    off += (bytes + 255) & ~(size_t)255;
    return p;
  };
  // R1: xb [Mpad][IN] bf16 -> h2 [Mpad][HID] bf16 -> stateB bf16 [N][256]
  char* R1 = alloc((size_t)Mpad * ((IN > HID) ? IN : HID) * 2);
  // R2: h1 [Mpad][HID] bf16 -> stateA bf16 [N][256]
  char* R2 = alloc((size_t)Mpad * HID * 2);
  // R4: h0b bf16 [Mpad][OUTD] (persistent teleport term)
  char* R4 = alloc((size_t)Mpad * OUTD * 2);
  int*   deg    = (int*)alloc((size_t)N * 4);
  int*   rowptr = (int*)alloc((size_t)(N + 1) * 4);
  int*   cursor = (int*)alloc((size_t)N * 4);
  float* dinv   = (float*)alloc((size_t)N * 4);
  int*   bsum   = (int*)alloc((size_t)256 * 4);
  i32x2* edge   = (i32x2*)alloc((size_t)(E + N + 8) * 8);  // +8: prefetch pad
  unsigned short* W1t = (unsigned short*)alloc((size_t)IN * HID * 2);
  unsigned short* W2t = (unsigned short*)alloc((size_t)HID * HID * 2);
  unsigned short* W3t = (unsigned short*)alloc((size_t)HID * OUTD * 2);
  (void)ws_size; (void)n_in; (void)out_size;

  unsigned short* xb = (unsigned short*)R1;
  unsigned short* h1 = (unsigned short*)R2;
  unsigned short* h2 = (unsigned short*)R1;
  unsigned short* h0b = (unsigned short*)R4;
  unsigned short* stateA = (unsigned short*)R2;
  unsigned short* stateB = (unsigned short*)R1;

  // graph build
  hipMemsetAsync(deg, 0, (size_t)N * 4, stream);
  k_hist<<<(E + 255) / 256, 256, 0, stream>>>(dst, deg, E);
  const int nb = (N + 1023) / 1024;
  k_scanA<<<nb, 1024, 0, stream>>>(deg, rowptr, bsum, N);
  k_scanB<<<1, 64, 0, stream>>>(bsum, nb);
  k_scanC<<<(N + 256) / 256, 256, 0, stream>>>(rowptr, bsum, deg, dinv, cursor, N, nb);
  k_scatter<<<(E + N + 255) / 256, 256, 0, stream>>>(src, dst, cursor, edge, dinv, E, N);

  // converts
  {
    long total8 = (long)Mpad * IN / 8;
    k_f2b8<<<(int)((total8 + 255) / 256), 256, 0, stream>>>(x, xb, N, IN, total8);
    dim3 tb(256);
    k_wtrans<<<dim3(HID / 32, IN / 32), tb, 0, stream>>>(W1, W1t, IN, HID);
    k_wtrans<<<dim3(HID / 32, HID / 32), tb, 0, stream>>>(W2, W2t, HID, HID);
    k_wtrans<<<dim3(OUTD / 32, HID / 32), tb, 0, stream>>>(W3, W3t, HID, OUTD);
  }

  // MLP encoder (MFMA); GEMM3 emits bf16 h0b directly
  {
    dim3 blk(256);
    dim3 g1(HID / 128, Mpad / 128);
    k_gemm_mfma<true, true><<<g1, blk, 0, stream>>>(xb, W1t, b1, h1, HID, IN);
    k_gemm_mfma<true, true><<<g1, blk, 0, stream>>>(h1, W2t, b2, h2, HID, HID);
    dim3 g3(OUTD / 128, Mpad / 128);
    k_gemm_mfma<true, false><<<g3, blk, 0, stream>>>(h2, W3t, b3, h0b, OUTD, HID);
  }

  // APPNP propagation: step0 reads h0b; steps ping-pong stateA/B; final -> d_out
  {
    const int nblk = (N + 3) / 4;
    const unsigned short* cur = h0b;
    for (int step = 0; step < K_STEPS - 1; ++step) {
      unsigned short* dbuf = (step % 2 == 0) ? stateA : stateB;
      k_appnp_b16<false><<<nblk, 256, 0, stream>>>(cur, h0b, dbuf, rowptr, edge, dinv, N);
      cur = dbuf;
    }
    k_appnp_b16<true><<<nblk, 256, 0, stream>>>(cur, h0b, d_out, rowptr, edge, dinv, N);
  }
}